// Round 2
// baseline (8326.101 us; speedup 1.0000x reference)
//
#include <hip/hip_runtime.h>
#include <math.h>

// LNN: BS=16384, d=32 (n=16), HID=512. All fp32.
// Per-sample: H = W1 D1 W1^T + M D2 M^T,  M = (W1^T diag(s1)) W2.
// out[:,0:16]=qd=x[:,16:32]; out[:,16:32]=pinv(H[16:,16:]) @ (jac[:16]-H[16:,:16]@qd)
// pinv via symmetric Jacobi eig (fp64) with JAX rcond = 10*16*eps_f32.

#define MPAD 516  // padded M row stride (floats); 516%32==4 -> 4-way instead of 32-way conflicts

#define OFF_M    0
#define OFF_S1   (32*MPAD)
#define OFF_DZ1  (OFF_S1 + 512)
#define OFF_G2   (OFF_DZ1 + 512)
#define OFF_D2   (OFF_G2 + 512)
#define OFF_U    (OFF_D2 + 512)
#define OFF_X    (OFF_U + 512)
#define OFF_JAC  (OFF_X + 32)
#define OFF_H    (OFF_JAC + 16)      // [16][33]
#define OFF_H2   (OFF_H + 16*33)     // [16][33]
#define OFF_AUG  (OFF_H2 + 16*33)    // [16][17]
#define OFF_F    (OFF_AUG + 16*17)
#define OFF_PIV  (OFF_F + 16)
#define SMEM_FLOATS (OFF_PIV + 4)
#define SMEM_BYTES  (SMEM_FLOATS * 4)   // 81872 B -> 2 blocks/CU

#define JAX_RCOND 1.9073486e-5   // 10 * max(M,N)=16 * eps_f32(1.1920929e-7)
#define NSWEEP 5

__device__ __forceinline__ void pairpq(int r, int m, int& p, int& q) {
    // round-robin tournament: P[0]=0 fixed, P[k]=1+((k-1+r)%15); pair m = (P[m],P[15-m])
    p = (m == 0) ? 0 : 1 + (m - 1 + r) % 15;
    q = 1 + (14 - m + r) % 15;
}

extern "C" __global__ __launch_bounds__(256, 2)
void lnn_kernel(const float* __restrict__ x,
                const float* __restrict__ W1, const float* __restrict__ b1,
                const float* __restrict__ W2, const float* __restrict__ b2,
                const float* __restrict__ W3,
                float* __restrict__ out)
{
    const int b = blockIdx.x;
    const int t = threadIdx.x;
    const int lane = t & 63;
    const int w = t >> 6;

    extern __shared__ float sm[];
    float* s_M   = sm + OFF_M;    // union: ws1T[512][32] -> M[32][MPAD] -> Jacobi workspace
    float* s_s1  = sm + OFF_S1;
    float* s_dz1 = sm + OFF_DZ1;  // h1 first, then dz1 = s1*u
    float* s_g2  = sm + OFF_G2;   // g2 first, then d1 = s1*(1-s1)*u
    float* s_d2  = sm + OFF_D2;
    float* s_u   = sm + OFF_U;
    float* s_x   = sm + OFF_X;
    float* s_jac = sm + OFF_JAC;
    float* s_H   = sm + OFF_H;
    float* s_H2  = sm + OFF_H2;
    float* s_aug = sm + OFF_AUG;

    // ---- phase 0: load x row; write qd half of output ----
    if (t < 32) s_x[t] = x[b*32 + t];
    if (t < 16) out[b*32 + t] = x[b*32 + 16 + t];
    __syncthreads();

    // ---- phase 1: z1 -> s1, h1 ----
    #pragma unroll
    for (int rep = 0; rep < 2; ++rep) {
        const int j = t + rep*256;
        float z = b1[j];
        #pragma unroll
        for (int i = 0; i < 32; ++i) z = fmaf(s_x[i], W1[i*512 + j], z);
        const float e = expf(-fabsf(z));
        const float s = (z >= 0.f) ? 1.f/(1.f+e) : e/(1.f+e);     // sigmoid
        s_s1[j]  = s;
        s_dz1[j] = fmaxf(z, 0.f) + log1pf(e);                     // softplus (h1)
    }
    __syncthreads();

    // ---- phase 2a: ws1T[j][i] = W1[i][j]*s1[j] ----
    {
        const int i = t & 31, jj = t >> 5;
        for (int j = jj; j < 512; j += 8)
            s_M[j*32 + i] = W1[i*512 + j] * s_s1[j];
    }

    // ---- phase 2b: z2 -> g2, d2 ----
    {
        const float2 b2v = ((const float2*)b2)[t];
        float z2a = b2v.x, z2b = b2v.y;
        const float2* W2v2 = (const float2*)W2;
        #pragma unroll 4
        for (int j = 0; j < 512; ++j) {
            const float h1j = s_dz1[j];
            const float2 wv = W2v2[j*256 + t];
            z2a = fmaf(h1j, wv.x, z2a);
            z2b = fmaf(h1j, wv.y, z2b);
        }
        const float2 w3v = ((const float2*)W3)[t];
        const float ea = expf(-fabsf(z2a));
        const float sa = (z2a >= 0.f) ? 1.f/(1.f+ea) : ea/(1.f+ea);
        const float eb = expf(-fabsf(z2b));
        const float sb = (z2b >= 0.f) ? 1.f/(1.f+eb) : eb/(1.f+eb);
        s_g2[2*t]   = w3v.x * sa;
        s_g2[2*t+1] = w3v.y * sb;
        s_d2[2*t]   = w3v.x * sa * (1.f - sa);
        s_d2[2*t+1] = w3v.y * sb * (1.f - sb);
    }
    __syncthreads();

    // ---- phase 3: GEMM M = ws1 @ W2; fused u = W2 @ g2 ----
    float acc[8][8];
    #pragma unroll
    for (int ii = 0; ii < 8; ++ii)
        #pragma unroll
        for (int kk = 0; kk < 8; ++kk) acc[ii][kk] = 0.f;

    float g2f[8];
    #pragma unroll
    for (int q = 0; q < 8; ++q) g2f[q] = s_g2[lane*8 + q];

    {
        const float4* W2v4 = (const float4*)W2;
        const int iw = w*8;
        for (int j = 0; j < 512; ++j) {
            const float4 bb0 = W2v4[j*128 + lane*2];
            const float4 bb1 = W2v4[j*128 + lane*2 + 1];
            const float4 a0 = *(const float4*)(s_M + j*32 + iw);
            const float4 a1 = *(const float4*)(s_M + j*32 + iw + 4);
            const float av[8] = {a0.x,a0.y,a0.z,a0.w,a1.x,a1.y,a1.z,a1.w};
            const float bv[8] = {bb0.x,bb0.y,bb0.z,bb0.w,bb1.x,bb1.y,bb1.z,bb1.w};
            #pragma unroll
            for (int ii = 0; ii < 8; ++ii)
                #pragma unroll
                for (int kk = 0; kk < 8; ++kk)
                    acc[ii][kk] = fmaf(av[ii], bv[kk], acc[ii][kk]);
            if ((j & 3) == w) {   // wave-uniform
                float p = 0.f;
                #pragma unroll
                for (int kk = 0; kk < 8; ++kk) p = fmaf(bv[kk], g2f[kk], p);
                #pragma unroll
                for (int off = 32; off >= 1; off >>= 1) p += __shfl_xor(p, off);
                if (lane == 0) s_u[j] = p;
            }
        }
    }
    __syncthreads();

    // ---- phase 4: write M (overlays ws1T); dz1 = s1*u; d1 = dz1*(1-s1) ----
    {
        const int iw = w*8;
        #pragma unroll
        for (int ii = 0; ii < 8; ++ii) {
            float* rowp = s_M + (iw+ii)*MPAD + lane*8;
            *(float4*)(rowp)     = make_float4(acc[ii][0],acc[ii][1],acc[ii][2],acc[ii][3]);
            *(float4*)(rowp + 4) = make_float4(acc[ii][4],acc[ii][5],acc[ii][6],acc[ii][7]);
        }
    }
    #pragma unroll
    for (int rep = 0; rep < 2; ++rep) {
        const int j = t + rep*256;
        const float uj = s_u[j], s = s_s1[j];
        const float dz = uj * s;
        s_dz1[j] = dz;
        s_g2[j]  = dz * (1.f - s);
    }
    __syncthreads();

    // ---- phase 5: jac partials ----
    {
        const int i = t & 15, sl = t >> 4;
        float p = 0.f;
        const int j0 = sl*32;
        #pragma unroll 8
        for (int jj = 0; jj < 32; ++jj) p = fmaf(W1[i*512 + j0 + jj], s_dz1[j0 + jj], p);
        s_aug[i*17 + sl] = p;
    }
    __syncthreads();

    // ---- phase 6: fold jac; term2 (waves 0,1) || term1 (waves 2,3) ----
    if (t < 16) {
        float p = 0.f;
        for (int sl = 0; sl < 16; ++sl) p += s_aug[t*17 + sl];
        s_jac[t] = p;
    }
    {
        const int tt = t & 127;
        const int i0 = 16 + 2*(tt >> 4);
        const int c0 = 2*(tt & 15);
        if (t < 128) {
            float h00=0.f,h01=0.f,h10=0.f,h11=0.f;
            const float4* Mi0 = (const float4*)(s_M + i0*MPAD);
            const float4* Mi1 = (const float4*)(s_M + (i0+1)*MPAD);
            const float4* Mc0 = (const float4*)(s_M + c0*MPAD);
            const float4* Mc1 = (const float4*)(s_M + (c0+1)*MPAD);
            const float4* d2v = (const float4*)s_d2;
            for (int q = 0; q < 128; ++q) {
                const float4 d  = d2v[q];
                const float4 a0 = Mi0[q], a1 = Mi1[q];
                const float4 m0 = Mc0[q], m1 = Mc1[q];
                float t0, t1;
                t0 = a0.x*d.x; t1 = a1.x*d.x;
                h00=fmaf(t0,m0.x,h00); h01=fmaf(t0,m1.x,h01); h10=fmaf(t1,m0.x,h10); h11=fmaf(t1,m1.x,h11);
                t0 = a0.y*d.y; t1 = a1.y*d.y;
                h00=fmaf(t0,m0.y,h00); h01=fmaf(t0,m1.y,h01); h10=fmaf(t1,m0.y,h10); h11=fmaf(t1,m1.y,h11);
                t0 = a0.z*d.z; t1 = a1.z*d.z;
                h00=fmaf(t0,m0.z,h00); h01=fmaf(t0,m1.z,h01); h10=fmaf(t1,m0.z,h10); h11=fmaf(t1,m1.z,h11);
                t0 = a0.w*d.w; t1 = a1.w*d.w;
                h00=fmaf(t0,m0.w,h00); h01=fmaf(t0,m1.w,h01); h10=fmaf(t1,m0.w,h10); h11=fmaf(t1,m1.w,h11);
            }
            s_H[(i0-16)*33 + c0]     = h00;
            s_H[(i0-16)*33 + c0+1]   = h01;
            s_H[(i0-15)*33 + c0]     = h10;
            s_H[(i0-15)*33 + c0+1]   = h11;
        } else {
            float h00=0.f,h01=0.f,h10=0.f,h11=0.f;
            const float4* Wi0 = (const float4*)(W1 + i0*512);
            const float4* Wi1 = (const float4*)(W1 + (i0+1)*512);
            const float4* Wc0 = (const float4*)(W1 + c0*512);
            const float4* Wc1 = (const float4*)(W1 + (c0+1)*512);
            const float4* d1v = (const float4*)s_g2;
            for (int q = 0; q < 128; ++q) {
                const float4 d  = d1v[q];
                const float4 a0 = Wi0[q], a1 = Wi1[q];
                const float4 m0 = Wc0[q], m1 = Wc1[q];
                float t0, t1;
                t0 = a0.x*d.x; t1 = a1.x*d.x;
                h00=fmaf(t0,m0.x,h00); h01=fmaf(t0,m1.x,h01); h10=fmaf(t1,m0.x,h10); h11=fmaf(t1,m1.x,h11);
                t0 = a0.y*d.y; t1 = a1.y*d.y;
                h00=fmaf(t0,m0.y,h00); h01=fmaf(t0,m1.y,h01); h10=fmaf(t1,m0.y,h10); h11=fmaf(t1,m1.y,h11);
                t0 = a0.z*d.z; t1 = a1.z*d.z;
                h00=fmaf(t0,m0.z,h00); h01=fmaf(t0,m1.z,h01); h10=fmaf(t1,m0.z,h10); h11=fmaf(t1,m1.z,h11);
                t0 = a0.w*d.w; t1 = a1.w*d.w;
                h00=fmaf(t0,m0.w,h00); h01=fmaf(t0,m1.w,h01); h10=fmaf(t1,m0.w,h10); h11=fmaf(t1,m1.w,h11);
            }
            s_H2[(i0-16)*33 + c0]     = h00;
            s_H2[(i0-16)*33 + c0+1]   = h01;
            s_H2[(i0-15)*33 + c0]     = h10;
            s_H2[(i0-15)*33 + c0+1]   = h11;
        }
    }
    __syncthreads();

    // ---- phase 7: aug = [A | rhs] ----
    {
        const int r = t >> 4, c = t & 15;
        s_aug[r*17 + c] = s_H[r*33 + 16 + c] + s_H2[r*33 + 16 + c];
    }
    if (t < 16) {
        float p = s_jac[t];
        #pragma unroll
        for (int c = 0; c < 16; ++c)
            p -= (s_H[t*33 + c] + s_H2[t*33 + c]) * s_x[16 + c];
        s_aug[t*17 + 16] = p;
    }
    __syncthreads();

    // ---- phase 8: pinv via symmetric Jacobi eig (fp64), JAX rcond truncation ----
    // workspace overlays dead s_M region (66 KB free, we use <5 KB)
    double* Ad   = (double*)(sm + OFF_M);   // [16][17]
    double* Vd   = Ad + 16*17;              // [16][17]
    double* s_c  = Vd + 16*17;              // [8]
    double* s_sn = s_c + 8;                 // [8]
    double* s_il = s_sn + 8;                // [16] inv-eigenvalues (0 if cut)
    double* s_y  = s_il + 16;               // [16] V^T rhs

    {
        const int r = t >> 4, c = t & 15;
        Ad[r*17 + c] = 0.5 * ((double)s_aug[r*17 + c] + (double)s_aug[c*17 + r]);
        Vd[r*17 + c] = (r == c) ? 1.0 : 0.0;
    }
    __syncthreads();

    for (int sweep = 0; sweep < NSWEEP; ++sweep) {
        for (int rr = 0; rr < 15; ++rr) {
            if (t < 8) {
                int p, q; pairpq(rr, t, p, q);
                const double app = Ad[p*17 + p], aqq = Ad[q*17 + q], apq = Ad[p*17 + q];
                double cc = 1.0, ss = 0.0;
                if (apq != 0.0) {
                    const double tau = (aqq - app) / (2.0 * apq);
                    const double tt = ((tau >= 0.0) ? 1.0 : -1.0) / (fabs(tau) + sqrt(1.0 + tau*tau));
                    cc = 1.0 / sqrt(1.0 + tt*tt);
                    ss = tt * cc;
                }
                s_c[t] = cc; s_sn[t] = ss;
            }
            __syncthreads();
            if (t < 128) {
                // rows: A <- J^T A
                const int m = t >> 4, j = t & 15;
                int p, q; pairpq(rr, m, p, q);
                const double cc = s_c[m], ss = s_sn[m];
                const double ap = Ad[p*17 + j], aq = Ad[q*17 + j];
                Ad[p*17 + j] = cc*ap - ss*aq;
                Ad[q*17 + j] = ss*ap + cc*aq;
            } else {
                // V <- V J (independent of A row/col updates)
                const int m = (t >> 4) & 7, i = t & 15;
                int p, q; pairpq(rr, m, p, q);
                const double cc = s_c[m], ss = s_sn[m];
                const double vp = Vd[i*17 + p], vq = Vd[i*17 + q];
                Vd[i*17 + p] = cc*vp - ss*vq;
                Vd[i*17 + q] = ss*vp + cc*vq;
            }
            __syncthreads();
            if (t < 128) {
                // cols: A <- A J
                const int m = t >> 4, i = t & 15;
                int p, q; pairpq(rr, m, p, q);
                const double cc = s_c[m], ss = s_sn[m];
                const double ap = Ad[i*17 + p], aq = Ad[i*17 + q];
                Ad[i*17 + p] = cc*ap - ss*aq;
                Ad[i*17 + q] = ss*ap + cc*aq;
            }
            __syncthreads();
        }
    }

    // truncated inverse eigenvalues (JAX pinv: keep sigma > rcond * sigma_max)
    if (t == 0) {
        double mx = 0.0;
        #pragma unroll
        for (int i = 0; i < 16; ++i) mx = fmax(mx, fabs(Ad[i*17 + i]));
        const double cut = JAX_RCOND * mx;
        #pragma unroll
        for (int i = 0; i < 16; ++i) {
            const double l = Ad[i*17 + i];
            s_il[i] = (fabs(l) > cut) ? (1.0 / l) : 0.0;
        }
    }
    __syncthreads();

    // y = V^T rhs
    if (t < 16) {
        double a = 0.0;
        #pragma unroll
        for (int r = 0; r < 16; ++r) a += Vd[r*17 + t] * (double)s_aug[r*17 + 16];
        s_y[t] = a;
    }
    __syncthreads();

    // qdd = V (il .* y)
    if (t < 16) {
        double a = 0.0;
        #pragma unroll
        for (int i = 0; i < 16; ++i) a += Vd[t*17 + i] * (s_il[i] * s_y[i]);
        out[b*32 + 16 + t] = (float)a;
    }
}

extern "C" void kernel_launch(void* const* d_in, const int* in_sizes, int n_in,
                              void* d_out, int out_size, void* d_ws, size_t ws_size,
                              hipStream_t stream) {
    const float* x  = (const float*)d_in[0];
    const float* W1 = (const float*)d_in[1];
    const float* b1 = (const float*)d_in[2];
    const float* W2 = (const float*)d_in[3];
    const float* b2 = (const float*)d_in[4];
    const float* W3 = (const float*)d_in[5];
    float* out = (float*)d_out;
    const int bs = in_sizes[0] / 32;

    hipFuncSetAttribute((const void*)lnn_kernel,
                        hipFuncAttributeMaxDynamicSharedMemorySize, SMEM_BYTES);
    lnn_kernel<<<dim3(bs), dim3(256), SMEM_BYTES, stream>>>(x, W1, b1, W2, b2, W3, out);
}

// Round 3
// 7297.220 us; speedup vs baseline: 1.1410x; 1.1410x over previous
//
#include <hip/hip_runtime.h>
#include <math.h>

// LNN: BS=16384, d=32 (n=16), HID=512. All fp32.
// H = W1 D1 W1^T + M D2 M^T,  M = (W1^T diag(s1)) W2,  jac = W1 (s1*u),
// u = W2 (W3*s2), e1 = u(1-s1)/s1 so term1 = ws1T^T diag(e1) ws1T.
// out[:, :16] = qd = x[:,16:]; out[:,16:] = pinv(A) rhs  (fp64 Jacobi eig, JAX rcond).

#define MPAD 516
#define NSWEEP 5
#define JAX_RCOND 1.9073486e-5   // 10 * 16 * eps_f32

// LDS float offsets
#define OFF_M    0                 // ws1T[512][32] -> M[32][516] -> fp64 Jacobi ws
#define OFF_S1   16512
#define OFF_H1   (OFF_S1+512)      // h1, later e1
#define OFF_G2   (OFF_H1+512)      // g2, later jac partials [16][16]
#define OFF_D2   (OFF_G2+512)
#define OFF_U    (OFF_D2+512)
#define OFF_X    (OFF_U+512)
#define OFF_JAC  (OFF_X+32)
#define OFF_T1   (OFF_JAC+16)      // [16][33]
#define OFF_T2   (OFF_T1+528)      // [16][33]
#define OFF_AUG  (OFF_T2+528)      // [16][17]
#define SMEM_FLOATS (OFF_AUG+272)
#define SMEM_BYTES  (SMEM_FLOATS*4)   // 81792 B -> 2 blocks/CU

__device__ __forceinline__ void pairpq(int r, int m, int& p, int& q) {
    p = (m == 0) ? 0 : 1 + (m - 1 + r) % 15;
    q = 1 + (14 - m + r) % 15;
}

__device__ __forceinline__ void wave_fence() {
    __builtin_amdgcn_wave_barrier();
    __builtin_amdgcn_s_waitcnt(0);     // drain vm/exp/lgkm; DS ops of a wave retire in order
    __builtin_amdgcn_wave_barrier();
}

extern "C" __global__ __launch_bounds__(256, 2)
void lnn_kernel(const float* __restrict__ x,
                const float* __restrict__ W1, const float* __restrict__ b1,
                const float* __restrict__ W2, const float* __restrict__ b2,
                const float* __restrict__ W3,
                float* __restrict__ out)
{
    const int b = blockIdx.x;
    const int t = threadIdx.x;
    const int lane = t & 63;
    const int w = t >> 6;

    extern __shared__ float sm[];
    float* s_wsT = sm + OFF_M;    // ws1T[j][i], j-major stride 32
    float* s_Mf  = sm + OFF_M;    // M[32][MPAD] (overlays ws1T later)
    float* s_s1  = sm + OFF_S1;
    float* s_h1  = sm + OFF_H1;   // h1 -> e1
    float* s_g2  = sm + OFF_G2;   // g2 -> jac partials
    float* s_d2  = sm + OFF_D2;
    float* s_u   = sm + OFF_U;
    float* s_x   = sm + OFF_X;
    float* s_jac = sm + OFF_JAC;
    float* s_T1  = sm + OFF_T1;
    float* s_T2  = sm + OFF_T2;
    float* s_aug = sm + OFF_AUG;

    // ---- P0: x row; qd half of output ----
    if (t < 32) s_x[t] = x[b*32 + t];
    if (t < 16) out[b*32 + t] = x[b*32 + 16 + t];
    __syncthreads();

    // ---- P1: z1 -> s1, h1 (coalesced W1 row reads) ----
    #pragma unroll
    for (int rep = 0; rep < 2; ++rep) {
        const int j = t + rep*256;
        float z = b1[j];
        #pragma unroll
        for (int i = 0; i < 32; ++i) z = fmaf(s_x[i], W1[i*512 + j], z);
        const float e = expf(-fabsf(z));
        const float s = (z >= 0.f) ? 1.f/(1.f+e) : e/(1.f+e);
        s_s1[j] = s;
        s_h1[j] = fmaxf(z, 0.f) + log1pf(e);
    }
    __syncthreads();

    // ---- P1b: ws1T[j][i] = W1[i][j]*s1[j] (conflict-free writes) ----
    {
        const int i = t & 31, jj = t >> 5;
        for (int j = jj; j < 512; j += 8)
            s_wsT[j*32 + i] = W1[i*512 + j] * s_s1[j];
    }
    __syncthreads();

    // ---- P2: GEMM M = ws1 @ W2 (col-split: wave w -> cols w*128.., lane: 4 rgrp x 16 cgrp)
    //          fused z2 accumulation (each lane's own 8 cols) ----
    const int r0 = (lane >> 4) * 8;
    const int c0 = w*128 + (lane & 15) * 8;

    float acc[8][8];
    #pragma unroll
    for (int ii = 0; ii < 8; ++ii)
        #pragma unroll
        for (int kk = 0; kk < 8; ++kk) acc[ii][kk] = 0.f;

    float zacc[8];
    {
        const float4 bz0 = *(const float4*)(b2 + c0);
        const float4 bz1 = *(const float4*)(b2 + c0 + 4);
        zacc[0]=bz0.x; zacc[1]=bz0.y; zacc[2]=bz0.z; zacc[3]=bz0.w;
        zacc[4]=bz1.x; zacc[5]=bz1.y; zacc[6]=bz1.z; zacc[7]=bz1.w;
    }

    {
        const float4* W2v4 = (const float4*)W2;
        const int cq = c0 >> 2;
        #pragma unroll 2
        for (int j = 0; j < 512; ++j) {
            const float4 bb0 = W2v4[j*128 + cq];
            const float4 bb1 = W2v4[j*128 + cq + 1];
            const float4 a0 = *(const float4*)(s_wsT + j*32 + r0);
            const float4 a1 = *(const float4*)(s_wsT + j*32 + r0 + 4);
            const float h1j = s_h1[j];
            const float av[8] = {a0.x,a0.y,a0.z,a0.w,a1.x,a1.y,a1.z,a1.w};
            const float bv[8] = {bb0.x,bb0.y,bb0.z,bb0.w,bb1.x,bb1.y,bb1.z,bb1.w};
            #pragma unroll
            for (int ii = 0; ii < 8; ++ii)
                #pragma unroll
                for (int kk = 0; kk < 8; ++kk)
                    acc[ii][kk] = fmaf(av[ii], bv[kk], acc[ii][kk]);
            #pragma unroll
            for (int kk = 0; kk < 8; ++kk)
                zacc[kk] = fmaf(h1j, bv[kk], zacc[kk]);
        }
    }

    // z2 -> g2, d2 for own 8 cols
    {
        const float4 w30 = *(const float4*)(W3 + c0);
        const float4 w31 = *(const float4*)(W3 + c0 + 4);
        const float w3v[8] = {w30.x,w30.y,w30.z,w30.w,w31.x,w31.y,w31.z,w31.w};
        #pragma unroll
        for (int kk = 0; kk < 8; ++kk) {
            const float z = zacc[kk];
            const float e = expf(-fabsf(z));
            const float sg = (z >= 0.f) ? 1.f/(1.f+e) : e/(1.f+e);
            s_g2[c0+kk] = w3v[kk] * sg;
            s_d2[c0+kk] = w3v[kk] * sg * (1.f - sg);
        }
    }
    __syncthreads();

    // ---- P3: u[j] = W2[j,:] . g2 (wave w -> j in [w*128, w*128+128)) ----
    {
        float g2f[8];
        {
            const float4 ga = *(const float4*)(s_g2 + lane*8);
            const float4 gb = *(const float4*)(s_g2 + lane*8 + 4);
            g2f[0]=ga.x; g2f[1]=ga.y; g2f[2]=ga.z; g2f[3]=ga.w;
            g2f[4]=gb.x; g2f[5]=gb.y; g2f[6]=gb.z; g2f[7]=gb.w;
        }
        for (int jj = 0; jj < 128; ++jj) {
            const int j = w*128 + jj;
            const float4 ra = *(const float4*)(W2 + j*512 + lane*8);
            const float4 rb = *(const float4*)(W2 + j*512 + lane*8 + 4);
            float p = ra.x*g2f[0];
            p = fmaf(ra.y, g2f[1], p); p = fmaf(ra.z, g2f[2], p); p = fmaf(ra.w, g2f[3], p);
            p = fmaf(rb.x, g2f[4], p); p = fmaf(rb.y, g2f[5], p);
            p = fmaf(rb.z, g2f[6], p); p = fmaf(rb.w, g2f[7], p);
            #pragma unroll
            for (int off = 32; off >= 1; off >>= 1) p += __shfl_xor(p, off);
            if (lane == 0) s_u[j] = p;
        }
    }
    __syncthreads();

    // ---- P4: e1 = u(1-s1)/s1 (into s_h1); jac partials (into s_g2) ----
    #pragma unroll
    for (int rep = 0; rep < 2; ++rep) {
        const int j = t + rep*256;
        const float uj = s_u[j], s = s_s1[j];
        s_h1[j] = uj * (1.f - s) / s;
    }
    {
        const int i = t & 15, seg = t >> 4;
        float p = 0.f;
        #pragma unroll 8
        for (int jj = 0; jj < 32; ++jj) {
            const int j = seg*32 + jj;
            p = fmaf(s_wsT[j*32 + i], s_u[j], p);
        }
        s_g2[seg*16 + i] = p;
    }
    __syncthreads();

    // ---- P5: fold jac; term1 from LDS ws1T with e1 weights ----
    if (t < 16) {
        float p = 0.f;
        #pragma unroll
        for (int seg = 0; seg < 16; ++seg) p += s_g2[seg*16 + t];
        s_jac[t] = p;
    }
    const int i5 = 16 + (t >> 4);
    const int c5 = 2 * (t & 15);
    {
        float t1a = 0.f, t1b = 0.f;
        #pragma unroll 4
        for (int j = 0; j < 512; ++j) {
            const float e   = s_h1[j];
            const float wsi = s_wsT[j*32 + i5];
            const float tt  = wsi * e;
            t1a = fmaf(tt, s_wsT[j*32 + c5],     t1a);
            t1b = fmaf(tt, s_wsT[j*32 + c5 + 1], t1b);
        }
        s_T1[(i5-16)*33 + c5]     = t1a;
        s_T1[(i5-16)*33 + c5 + 1] = t1b;
    }
    __syncthreads();   // ws1T reads done before M overwrite

    // ---- P6: write M[32][MPAD] from acc (overlays ws1T) ----
    {
        #pragma unroll
        for (int ii = 0; ii < 8; ++ii) {
            float* rp = s_Mf + (r0+ii)*MPAD + c0;
            *(float4*)(rp)     = make_float4(acc[ii][0],acc[ii][1],acc[ii][2],acc[ii][3]);
            *(float4*)(rp + 4) = make_float4(acc[ii][4],acc[ii][5],acc[ii][6],acc[ii][7]);
        }
    }
    __syncthreads();

    // ---- P7: term2 = M D2 M^T (rows 16..31 x cols 0..31) ----
    {
        float h0 = 0.f, h1v = 0.f;
        const float4* d2v = (const float4*)s_d2;
        const float4* Mi = (const float4*)(s_Mf + i5*MPAD);
        const float4* Ma = (const float4*)(s_Mf + c5*MPAD);
        const float4* Mb = (const float4*)(s_Mf + (c5+1)*MPAD);
        for (int q = 0; q < 128; ++q) {
            const float4 d  = d2v[q];
            const float4 mi = Mi[q];
            const float4 ma = Ma[q];
            const float4 mb = Mb[q];
            float tt;
            tt = mi.x*d.x; h0 = fmaf(tt, ma.x, h0); h1v = fmaf(tt, mb.x, h1v);
            tt = mi.y*d.y; h0 = fmaf(tt, ma.y, h0); h1v = fmaf(tt, mb.y, h1v);
            tt = mi.z*d.z; h0 = fmaf(tt, ma.z, h0); h1v = fmaf(tt, mb.z, h1v);
            tt = mi.w*d.w; h0 = fmaf(tt, ma.w, h0); h1v = fmaf(tt, mb.w, h1v);
        }
        s_T2[(i5-16)*33 + c5]     = h0;
        s_T2[(i5-16)*33 + c5 + 1] = h1v;
    }
    __syncthreads();

    // ---- P8: aug = [A | rhs] ----
    {
        const int r = t >> 4, c = t & 15;
        s_aug[r*17 + c] = s_T1[r*33 + 16 + c] + s_T2[r*33 + 16 + c];
    }
    if (t < 16) {
        float p = s_jac[t];
        #pragma unroll
        for (int c = 0; c < 16; ++c)
            p -= (s_T1[t*33 + c] + s_T2[t*33 + c]) * s_x[16 + c];
        s_aug[t*17 + 16] = p;
    }
    __syncthreads();

    // ---- P9: single-wave fp64 Jacobi pinv solve (no block barriers) ----
    if (w != 0) return;

    double* Ad  = (double*)sm;       // [16][17]
    double* Vd  = Ad + 272;          // [16][17]
    double* c8  = Vd + 272;          // [8]
    double* sn8 = c8 + 8;            // [8]
    double* il  = sn8 + 8;           // [16]
    double* yv  = il + 16;           // [16]

    for (int idx = t; idx < 272; idx += 64) {
        const int r = idx / 17, c = idx - r*17;
        double a = 0.0;
        if (c < 16) a = 0.5 * ((double)s_aug[r*17 + c] + (double)s_aug[c*17 + r]);
        Ad[idx] = a;
        Vd[idx] = (c < 16 && r == c) ? 1.0 : 0.0;
    }
    wave_fence();

    for (int sweep = 0; sweep < NSWEEP; ++sweep) {
        for (int rr = 0; rr < 15; ++rr) {
            if (t < 8) {
                int p, q; pairpq(rr, t, p, q);
                const double app = Ad[p*17 + p], aqq = Ad[q*17 + q], apq = Ad[p*17 + q];
                double cc = 1.0, ss = 0.0;
                if (apq != 0.0) {
                    const double tau = (aqq - app) / (2.0 * apq);
                    const double tt = ((tau >= 0.0) ? 1.0 : -1.0) / (fabs(tau) + sqrt(1.0 + tau*tau));
                    cc = 1.0 / sqrt(1.0 + tt*tt);
                    ss = tt * cc;
                }
                c8[t] = cc; sn8[t] = ss;
            }
            wave_fence();
            #pragma unroll
            for (int k = 0; k < 2; ++k) {      // rows: A <- J^T A (128 items)
                const int id = t + 64*k;
                const int m = id >> 4, j = id & 15;
                int p, q; pairpq(rr, m, p, q);
                const double cc = c8[m], ss = sn8[m];
                const double ap = Ad[p*17 + j], aq = Ad[q*17 + j];
                Ad[p*17 + j] = cc*ap - ss*aq;
                Ad[q*17 + j] = ss*ap + cc*aq;
            }
            #pragma unroll
            for (int k = 0; k < 2; ++k) {      // V <- V J (128 items, disjoint array)
                const int id = t + 64*k;
                const int m = id >> 4, i = id & 15;
                int p, q; pairpq(rr, m, p, q);
                const double cc = c8[m], ss = sn8[m];
                const double vp = Vd[i*17 + p], vq = Vd[i*17 + q];
                Vd[i*17 + p] = cc*vp - ss*vq;
                Vd[i*17 + q] = ss*vp + cc*vq;
            }
            wave_fence();
            #pragma unroll
            for (int k = 0; k < 2; ++k) {      // cols: A <- A J (128 items)
                const int id = t + 64*k;
                const int m = id >> 4, i = id & 15;
                int p, q; pairpq(rr, m, p, q);
                const double cc = c8[m], ss = sn8[m];
                const double ap = Ad[i*17 + p], aq = Ad[i*17 + q];
                Ad[i*17 + p] = cc*ap - ss*aq;
                Ad[i*17 + q] = ss*ap + cc*aq;
            }
            wave_fence();
        }
    }

    if (t == 0) {
        double mx = 0.0;
        #pragma unroll
        for (int i = 0; i < 16; ++i) mx = fmax(mx, fabs(Ad[i*17 + i]));
        const double cut = JAX_RCOND * mx;
        #pragma unroll
        for (int i = 0; i < 16; ++i) {
            const double l = Ad[i*17 + i];
            il[i] = (fabs(l) > cut) ? (1.0 / l) : 0.0;
        }
    }
    wave_fence();

    if (t < 16) {
        double a = 0.0;
        #pragma unroll
        for (int r = 0; r < 16; ++r) a += Vd[r*17 + t] * (double)s_aug[r*17 + 16];
        yv[t] = a;
    }
    wave_fence();

    if (t < 16) {
        double a = 0.0;
        #pragma unroll
        for (int i = 0; i < 16; ++i) a += Vd[t*17 + i] * (il[i] * yv[i]);
        out[b*32 + 16 + t] = (float)a;
    }
}

extern "C" void kernel_launch(void* const* d_in, const int* in_sizes, int n_in,
                              void* d_out, int out_size, void* d_ws, size_t ws_size,
                              hipStream_t stream) {
    const float* x  = (const float*)d_in[0];
    const float* W1 = (const float*)d_in[1];
    const float* b1 = (const float*)d_in[2];
    const float* W2 = (const float*)d_in[3];
    const float* b2 = (const float*)d_in[4];
    const float* W3 = (const float*)d_in[5];
    float* out = (float*)d_out;
    const int bs = in_sizes[0] / 32;

    hipFuncSetAttribute((const void*)lnn_kernel,
                        hipFuncAttributeMaxDynamicSharedMemorySize, SMEM_BYTES);
    lnn_kernel<<<dim3(bs), dim3(256), SMEM_BYTES, stream>>>(x, W1, b1, W2, b2, W3, out);
}